// Round 11
// baseline (259.789 us; speedup 1.0000x reference)
//
#include <hip/hip_runtime.h>
#include <math.h>

#define TPB 256
#define NBMAX 2048          // buckets of 256 nodes -> supports N <= 524288

__device__ __forceinline__ float fsig(float x) {
    return __builtin_amdgcn_rcpf(1.f + __expf(-x));   // abs err ~1e-7; x->-inf => 0
}
__device__ __forceinline__ float ftanh(float x) {
    float t = __expf(2.f * fabsf(x));                  // t -> inf => r -> 1
    float r = 1.f - 2.f * __builtin_amdgcn_rcpf(t + 1.f);
    return copysignf(r, x);
}

__global__ __launch_bounds__(256) void k_zero(int* __restrict__ p, int n) {
    int i = blockIdx.x * 256 + threadIdx.x;
    if (i < n) p[i] = 0;
}

// ---------------- bucketed CSR build ----------------

// bucket histogram (bucket = dst >> 8), LDS-aggregated
__global__ __launch_bounds__(256) void k_bhist(const int* __restrict__ ei,
                                               int* __restrict__ bhist, int E, int NB) {
    __shared__ int h[NBMAX];
    for (int i = threadIdx.x; i < NB; i += 256) h[i] = 0;
    __syncthreads();
    int stride = gridDim.x * 256;
    for (int e = blockIdx.x * 256 + threadIdx.x; e < E; e += stride)
        atomicAdd(&h[ei[E + e] >> 8], 1);
    __syncthreads();
    for (int i = threadIdx.x; i < NB; i += 256) if (h[i]) atomicAdd(&bhist[i], h[i]);
}

// exclusive scan of bucket counts; bfill = bbase; sentinel entries
__global__ __launch_bounds__(256) void k_bscan(const int* __restrict__ bhist,
                                               int* __restrict__ bbase, int* __restrict__ bfill,
                                               int* __restrict__ row_start,
                                               int NB, int N, int E) {
    __shared__ int tsum[256];
    int tid = threadIdx.x;
    int per = (NB + 255) / 256;           // <= 8
    int loc[8]; int tot = 0;
    int base = tid * per;
#pragma unroll
    for (int j = 0; j < 8; j++) {
        int i = base + j;
        int v = (j < per && i < NB) ? bhist[i] : 0;
        loc[j] = v; tot += v;
    }
    tsum[tid] = tot;
    __syncthreads();
    for (int off = 1; off < 256; off <<= 1) {
        int t = (tid >= off) ? tsum[tid - off] : 0;
        __syncthreads();
        tsum[tid] += t;
        __syncthreads();
    }
    int run = tsum[tid] - tot;
#pragma unroll
    for (int j = 0; j < 8; j++) {
        int i = base + j;
        if (j < per && i < NB) { bbase[i] = run; bfill[i] = run; run += loc[j]; }
    }
    if (tid == 0) { bbase[NB] = E; row_start[N] = E; }
}

// bin edges into bucket-contiguous ebuf: {src | dlow<<24, weight}
__global__ __launch_bounds__(256) void k_bin(const int* __restrict__ ei,
                                             const float* __restrict__ ew,
                                             int* bfill, int2* __restrict__ ebuf,
                                             int E, int NB) {
    __shared__ int h[NBMAX];
    __shared__ int gb[NBMAX];
    const int EPT = 16;
    int tid = threadIdx.x;
    int base = blockIdx.x * 256 * EPT;
    for (int i = tid; i < NB; i += 256) h[i] = 0;
    __syncthreads();
    int src[EPT]; float w[EPT]; int bkt[EPT]; int lrank[EPT];
#pragma unroll
    for (int j = 0; j < EPT; j++) {
        int e = base + j * 256 + tid;              // coalesced
        if (e < E) {
            src[j] = ei[e]; int d = ei[E + e]; w[j] = ew[e];
            int b = d >> 8;
            bkt[j] = b | ((d & 255) << 16);
            lrank[j] = atomicAdd(&h[b], 1);
        } else bkt[j] = -1;
    }
    __syncthreads();
    for (int i = tid; i < NB; i += 256) gb[i] = h[i] ? atomicAdd(&bfill[i], h[i]) : 0;
    __syncthreads();
#pragma unroll
    for (int j = 0; j < EPT; j++) {
        if (bkt[j] >= 0) {
            int b = bkt[j] & 0xFFFF, dlow = (bkt[j] >> 16) & 0xFF;
            int2 v; v.x = src[j] | (dlow << 24); v.y = __float_as_int(w[j]);
            ebuf[gb[b] + lrank[j]] = v;
        }
    }
}

// per bucket (256 nodes): counts + weight sums -> row_start, dinv, final CSR,
// PLUS padded 32-slot table esl[node*32+rank]={src,w} (pads {0,0});
// fused first-layer prep: Y = dinv * X for this bucket's rows (contiguous)
__global__ __launch_bounds__(256) void k_bucket(const int2* __restrict__ ebuf,
                                                const int* __restrict__ bbase,
                                                int2* __restrict__ csr,
                                                int2* __restrict__ esl,
                                                int* __restrict__ row_start,
                                                float* __restrict__ dinv,
                                                const float4* __restrict__ X4,
                                                float4* __restrict__ Y4,
                                                int N, int E) {
    __shared__ int lcnt[256];
    __shared__ float wsum[256];
    __shared__ int lstart[256];
    __shared__ int sc[256];
    __shared__ float sdinv[256];
    int b = blockIdx.x, tid = threadIdx.x;
    int beg = bbase[b], end = bbase[b + 1];
    lcnt[tid] = 0; wsum[tid] = 0.f;
    __syncthreads();
    for (int i = beg + tid; i < end; i += 256) {
        int2 v = ebuf[i];
        int dlow = ((unsigned)v.x) >> 24;
        atomicAdd(&lcnt[dlow], 1);
        atomicAdd(&wsum[dlow], __int_as_float(v.y));
    }
    __syncthreads();
    int myc = lcnt[tid];
    sc[tid] = myc;
    __syncthreads();
    for (int off = 1; off < 256; off <<= 1) {
        int t = (tid >= off) ? sc[tid - off] : 0;
        __syncthreads();
        sc[tid] += t;
        __syncthreads();
    }
    lstart[tid] = sc[tid] - myc;
    int node = (b << 8) + tid;
    float dv = rsqrtf(1.0f + wsum[tid]);          // self-loop weight 1; deg >= 1
    sdinv[tid] = dv;
    if (node < N) {
        row_start[node] = beg + sc[tid] - myc;
        dinv[node] = dv;
    }
    lcnt[tid] = 0;
    __syncthreads();
    size_t nodeBase = (size_t)(b << 8) * 32;
    for (int i = beg + tid; i < end; i += 256) {
        int2 v = ebuf[i];
        int dlow = ((unsigned)v.x) >> 24;
        int rank = atomicAdd(&lcnt[dlow], 1);
        int2 o; o.x = v.x & 0x00FFFFFF; o.y = v.y;
        csr[beg + lstart[dlow] + rank] = o;        // full CSR (tail path)
        if (rank < 32) esl[nodeBase + dlow * 32 + rank] = o;  // slot table
    }
    __syncthreads();                               // lcnt now = deg
    // pad unused slots with {src=0, w=0} (coalesced over bucket)
    int nNodes = N - (b << 8); if (nNodes > 256) nNodes = 256;
    for (int i = tid; i < nNodes * 32; i += 256) {
        int r = i >> 5, j = i & 31;
        if (j >= lcnt[r]) { int2 z; z.x = 0; z.y = 0; esl[nodeBase + i] = z; }
    }
    // fused prep: Y rows for this bucket (8 float4 per node, contiguous)
    int limit = nNodes * 8;
    size_t base4 = ((size_t)b << 8) * 8;
    for (int i = tid; i < limit; i += 256) {
        float4 v = X4[base4 + i];
        float d = sdinv[i >> 3];
        float4 o; o.x = v.x * d; o.y = v.y * d; o.z = v.z * d; o.w = v.w * d;
        Y4[base4 + i] = o;
    }
}

// ---------------- per-layer compute ----------------

// AX[d,:] = dinv[d] * (Y[d,:] + sum_e w_e * Y[src_e,:])
// one wave per node; 8 lanes x float4 cover the 128B row; 8 edge slots x 4.
// Slot-table gather: ALL loads (esl x4, self, dinv, row_start) address-computable
// from wid alone -> dependent chain = esl -> Y only (depth 2). Pads have w=0.
__global__ __launch_bounds__(256) void k_gather(const float4* __restrict__ Y4,
                                                const int2* __restrict__ esl,
                                                const int* __restrict__ row_start,
                                                const int2* __restrict__ csr,
                                                const float* __restrict__ dinv,
                                                float4* __restrict__ AX4, int N) {
    int wid = (blockIdx.x * blockDim.x + threadIdx.x) >> 6;
    if (wid >= N) return;
    int lane = threadIdx.x & 63;
    int q = lane >> 3, c4 = lane & 7;
    const int2* ep = esl + (size_t)wid * 32 + q;
    int2 p0 = ep[0], p1 = ep[8], p2 = ep[16], p3 = ep[24];   // all in flight at once
    float di = dinv[wid];
    float4 self = Y4[(size_t)wid * 8 + c4];
    int rs = row_start[wid], re = row_start[wid + 1];        // tail check only
    float4 y0 = Y4[(size_t)p0.x * 8 + c4];
    float4 y1 = Y4[(size_t)p1.x * 8 + c4];
    float4 y2 = Y4[(size_t)p2.x * 8 + c4];
    float4 y3 = Y4[(size_t)p3.x * 8 + c4];
    float w0 = __int_as_float(p0.y), w1 = __int_as_float(p1.y);
    float w2 = __int_as_float(p2.y), w3 = __int_as_float(p3.y);
    float4 acc1, acc2;
    if (q == 0) acc1 = self; else { acc1.x = acc1.y = acc1.z = acc1.w = 0.f; }
    acc2.x = acc2.y = acc2.z = acc2.w = 0.f;
    acc1.x += w0 * y0.x; acc1.y += w0 * y0.y; acc1.z += w0 * y0.z; acc1.w += w0 * y0.w;
    acc2.x += w1 * y1.x; acc2.y += w1 * y1.y; acc2.z += w1 * y1.z; acc2.w += w1 * y1.w;
    acc1.x += w2 * y2.x; acc1.y += w2 * y2.y; acc1.z += w2 * y2.z; acc1.w += w2 * y2.w;
    acc2.x += w3 * y3.x; acc2.y += w3 * y3.y; acc2.z += w3 * y3.z; acc2.w += w3 * y3.w;
    // rare tail: deg > 32 (expected ~20 nodes of 100K) via full CSR
    if (re - rs > 32) {
        for (int e = rs + 32 + q; e < re; e += 8) {
            int2 t = csr[e];
            float4 yt = Y4[(size_t)t.x * 8 + c4];
            float wt = __int_as_float(t.y);
            acc1.x += wt * yt.x; acc1.y += wt * yt.y; acc1.z += wt * yt.z; acc1.w += wt * yt.w;
        }
    }
    acc1.x += acc2.x; acc1.y += acc2.y; acc1.z += acc2.z; acc1.w += acc2.w;
#pragma unroll
    for (int off = 8; off <= 32; off <<= 1) {
        acc1.x += __shfl_xor(acc1.x, off);
        acc1.y += __shfl_xor(acc1.y, off);
        acc1.z += __shfl_xor(acc1.z, off);
        acc1.w += __shfl_xor(acc1.w, off);
    }
    if (lane < 8) {
        float4 o; o.x = acc1.x * di; o.y = acc1.y * di; o.z = acc1.z * di; o.w = acc1.w * di;
        AX4[(size_t)wid * 8 + c4] = o;
    }
}

// 4-node W-reuse gates: block = 128 nodes; thread (r0=tid>>3, g8=tid&7) does
// nodes r0+32j, channels g8*4..+3 for I/T/O. Each W float4 read is reused
// across 4 nodes. Epilogue in-register (bS/wcs/sdv in LDS, fast transcendentals).
__global__ __launch_bounds__(256) void k_gates(const float* __restrict__ AX,
                                               const float* __restrict__ cw,
                                               const float* __restrict__ cb,
                                               const float* __restrict__ wc,
                                               const float* __restrict__ bg,
                                               const float* __restrict__ dinv,
                                               float* __restrict__ outRaw,
                                               float* __restrict__ outY,
                                               int N, int l, int isLast) {
    __shared__ float Ws[32][96];                   // [k][gate*32 + c]
    __shared__ float Xs[128][33];
    __shared__ float bS[96];
    __shared__ float wcs[32];
    __shared__ float sdv[128];
    int tid = threadIdx.x;
    for (int i = tid; i < 3072; i += 256) {
        int k = i / 96, ccol = i - k * 96;
        int g = ccol >> 5, o = ccol & 31;
        int j = (g == 0) ? 0 : ((g == 1) ? 4 : 6); // I, T, O convs on x
        Ws[k][ccol] = cw[(((l * 8 + j) * 32) + k) * 32 + o];
    }
    if (tid < 32) {
        int c = tid;
        bS[c]      = cb[((l * 8 + 0) * 32) + c] + cb[((l * 8 + 1) * 32) + c] + bg[((l * 4 + 0) * 32) + c];
        bS[32 + c] = cb[((l * 8 + 4) * 32) + c] + cb[((l * 8 + 5) * 32) + c] + bg[((l * 4 + 2) * 32) + c];
        bS[64 + c] = cb[((l * 8 + 6) * 32) + c] + cb[((l * 8 + 7) * 32) + c] + bg[((l * 4 + 3) * 32) + c];
        wcs[c]     = wc[((l * 3 + 2) * 32) + c];
    }
    int row0 = blockIdx.x * 128;
    for (int i = tid; i < 4096; i += 256) {
        int r = i >> 5, k = i & 31; int gr = row0 + r;
        Xs[r][k] = (gr < N) ? AX[(size_t)gr * 32 + k] : 0.f;
    }
    if (tid < 128) {
        int gr = row0 + tid;
        sdv[tid] = (gr < N) ? dinv[gr] : 0.f;
    }
    __syncthreads();
    int r0 = tid >> 3, g8 = tid & 7, cbase = g8 * 4;
    float aI[4][4], aT[4][4], aO[4][4];            // [node j][channel cc]
#pragma unroll
    for (int j = 0; j < 4; j++)
#pragma unroll
        for (int cc = 0; cc < 4; cc++) { aI[j][cc] = 0.f; aT[j][cc] = 0.f; aO[j][cc] = 0.f; }
#pragma unroll 4
    for (int k = 0; k < 32; k++) {
        float4 wI = *(const float4*)&Ws[k][cbase];
        float4 wT = *(const float4*)&Ws[k][32 + cbase];
        float4 wO = *(const float4*)&Ws[k][64 + cbase];
#pragma unroll
        for (int j = 0; j < 4; j++) {
            float xv = Xs[r0 + 32 * j][k];
            aI[j][0] += xv * wI.x; aI[j][1] += xv * wI.y; aI[j][2] += xv * wI.z; aI[j][3] += xv * wI.w;
            aT[j][0] += xv * wT.x; aT[j][1] += xv * wT.y; aT[j][2] += xv * wT.z; aT[j][3] += xv * wT.w;
            aO[j][0] += xv * wO.x; aO[j][1] += xv * wO.y; aO[j][2] += xv * wO.z; aO[j][3] += xv * wO.w;
        }
    }
#pragma unroll
    for (int j = 0; j < 4; j++) {
        int r = r0 + 32 * j;
        int gn = row0 + r;
        if (gn >= N) continue;
        float di = sdv[r];
        float4 v;
        float res[4];
#pragma unroll
        for (int cc = 0; cc < 4; cc++) {
            int c = cbase + cc;
            float I = fsig(aI[j][cc] + bS[c]);
            float T = ftanh(aT[j][cc] + bS[32 + c]);
            float C = I * T;                       // C_old = 0, F-gate dead
            float O = fsig(aO[j][cc] + wcs[c] * C + bS[64 + c]);
            float val = O * ftanh(C);
            res[cc] = isLast ? val : di * val;
        }
        v.x = res[0]; v.y = res[1]; v.z = res[2]; v.w = res[3];
        float* dst = isLast ? outRaw : outY;
        *(float4*)&dst[(size_t)gn * 32 + cbase] = v;
    }
}

extern "C" void kernel_launch(void* const* d_in, const int* in_sizes, int n_in,
                              void* d_out, int out_size, void* d_ws, size_t ws_size,
                              hipStream_t stream) {
    const float* X  = (const float*)d_in[0];
    const int*   ei = (const int*)d_in[1];
    const float* ew = (const float*)d_in[2];
    const float* cw = (const float*)d_in[3];
    const float* cb = (const float*)d_in[4];
    const float* wc = (const float*)d_in[5];
    const float* bg = (const float*)d_in[6];
    int N = in_sizes[0] / 32;
    int E = in_sizes[2];
    int L = in_sizes[3] / (8 * 32 * 32);
    float* out = (float*)d_out;
    int NB = (N + 255) >> 8;

    char* p = (char*)d_ws;
    auto alloc = [&](size_t bytes) -> char* {
        char* r = p; p += (bytes + 255) & ~(size_t)255; return r;
    };
    int*   bhist     = (int*)alloc((size_t)NB * 4);
    int*   bbase     = (int*)alloc((size_t)(NB + 1) * 4);
    int*   bfill     = (int*)alloc((size_t)NB * 4);
    int*   row_start = (int*)alloc((size_t)(N + 1) * 4);
    float* dinv      = (float*)alloc((size_t)N * 4);
    int2*  ebuf      = (int2*)alloc((size_t)E * 8);
    int2*  csr       = (int2*)alloc((size_t)E * 8);
    int2*  esl       = (int2*)alloc((size_t)N * 32 * 8);
    float* Y         = (float*)alloc((size_t)N * 32 * 4);
    float* AX        = (float*)alloc((size_t)N * 32 * 4);

    k_zero<<<(NB + 255) / 256, 256, 0, stream>>>(bhist, NB);
    k_bhist<<<512, 256, 0, stream>>>(ei, bhist, E, NB);
    k_bscan<<<1, 256, 0, stream>>>(bhist, bbase, bfill, row_start, NB, N, E);
    int nBin = (E + 4095) / 4096;
    k_bin<<<nBin, 256, 0, stream>>>(ei, ew, bfill, ebuf, E, NB);
    k_bucket<<<NB, 256, 0, stream>>>(ebuf, bbase, csr, esl, row_start, dinv,
                                     (const float4*)X, (float4*)Y, N, E);

    for (int l = 0; l < L; l++) {
        k_gather<<<(N + 3) / 4, 256, 0, stream>>>((const float4*)Y, esl, row_start,
                                                  csr, dinv, (float4*)AX, N);
        k_gates<<<(N + 127) / 128, 256, 0, stream>>>(AX, cw, cb, wc, bg, dinv,
                                                     out, Y, N, l, l == L - 1);
    }
}

// Round 12
// 247.989 us; speedup vs baseline: 1.0476x; 1.0476x over previous
//
#include <hip/hip_runtime.h>
#include <math.h>

#define TPB 256
#define NBMAX 2048          // buckets of 256 nodes -> supports N <= 524288

__device__ __forceinline__ float fsig(float x) {
    return __builtin_amdgcn_rcpf(1.f + __expf(-x));   // abs err ~1e-7; x->-inf => 0
}
__device__ __forceinline__ float ftanh(float x) {
    float t = __expf(2.f * fabsf(x));                  // t -> inf => r -> 1
    float r = 1.f - 2.f * __builtin_amdgcn_rcpf(t + 1.f);
    return copysignf(r, x);
}

__global__ __launch_bounds__(256) void k_zero(int* __restrict__ p, int n) {
    int i = blockIdx.x * 256 + threadIdx.x;
    if (i < n) p[i] = 0;
}

// ---------------- bucketed slot-table build ----------------

// bucket histogram (bucket = dst >> 8), LDS-aggregated
__global__ __launch_bounds__(256) void k_bhist(const int* __restrict__ ei,
                                               int* __restrict__ bhist, int E, int NB) {
    __shared__ int h[NBMAX];
    for (int i = threadIdx.x; i < NB; i += 256) h[i] = 0;
    __syncthreads();
    int stride = gridDim.x * 256;
    for (int e = blockIdx.x * 256 + threadIdx.x; e < E; e += stride)
        atomicAdd(&h[ei[E + e] >> 8], 1);
    __syncthreads();
    for (int i = threadIdx.x; i < NB; i += 256) if (h[i]) atomicAdd(&bhist[i], h[i]);
}

// exclusive scan of bucket counts; bfill = bbase
__global__ __launch_bounds__(256) void k_bscan(const int* __restrict__ bhist,
                                               int* __restrict__ bbase, int* __restrict__ bfill,
                                               int NB, int E) {
    __shared__ int tsum[256];
    int tid = threadIdx.x;
    int per = (NB + 255) / 256;           // <= 8
    int loc[8]; int tot = 0;
    int base = tid * per;
#pragma unroll
    for (int j = 0; j < 8; j++) {
        int i = base + j;
        int v = (j < per && i < NB) ? bhist[i] : 0;
        loc[j] = v; tot += v;
    }
    tsum[tid] = tot;
    __syncthreads();
    for (int off = 1; off < 256; off <<= 1) {
        int t = (tid >= off) ? tsum[tid - off] : 0;
        __syncthreads();
        tsum[tid] += t;
        __syncthreads();
    }
    int run = tsum[tid] - tot;
#pragma unroll
    for (int j = 0; j < 8; j++) {
        int i = base + j;
        if (j < per && i < NB) { bbase[i] = run; bfill[i] = run; run += loc[j]; }
    }
    if (tid == 0) bbase[NB] = E;
}

// bin edges into bucket-contiguous ebuf: {src | dlow<<24, weight}
__global__ __launch_bounds__(256) void k_bin(const int* __restrict__ ei,
                                             const float* __restrict__ ew,
                                             int* bfill, int2* __restrict__ ebuf,
                                             int E, int NB) {
    __shared__ int h[NBMAX];
    __shared__ int gb[NBMAX];
    const int EPT = 16;
    int tid = threadIdx.x;
    int base = blockIdx.x * 256 * EPT;
    for (int i = tid; i < NB; i += 256) h[i] = 0;
    __syncthreads();
    int src[EPT]; float w[EPT]; int bkt[EPT]; int lrank[EPT];
#pragma unroll
    for (int j = 0; j < EPT; j++) {
        int e = base + j * 256 + tid;              // coalesced
        if (e < E) {
            src[j] = ei[e]; int d = ei[E + e]; w[j] = ew[e];
            int b = d >> 8;
            bkt[j] = b | ((d & 255) << 16);
            lrank[j] = atomicAdd(&h[b], 1);
        } else bkt[j] = -1;
    }
    __syncthreads();
    for (int i = tid; i < NB; i += 256) gb[i] = h[i] ? atomicAdd(&bfill[i], h[i]) : 0;
    __syncthreads();
#pragma unroll
    for (int j = 0; j < EPT; j++) {
        if (bkt[j] >= 0) {
            int b = bkt[j] & 0xFFFF, dlow = (bkt[j] >> 16) & 0xFF;
            int2 v; v.x = src[j] | (dlow << 24); v.y = __float_as_int(w[j]);
            ebuf[gb[b] + lrank[j]] = v;
        }
    }
}

// per bucket (256 nodes): native LDS atomics (ds_add) for count + weight sum;
// scatter rank<32 into 32-slot table esl, rank>=32 to global overflow list;
// pad unused slots {0,0}; dinv = rsqrt(1+wsum); fused Y = dinv*X prep.
__global__ __launch_bounds__(256) void k_bucket(const int2* __restrict__ ebuf,
                                                const int* __restrict__ bbase,
                                                int2* __restrict__ esl,
                                                int4* __restrict__ ovbuf,
                                                int* __restrict__ ovcnt,
                                                float* __restrict__ dinv,
                                                const float4* __restrict__ X4,
                                                float4* __restrict__ Y4,
                                                int N, int E) {
    __shared__ int lcnt[256];
    __shared__ float wsum[256];
    __shared__ float sdinv[256];
    int b = blockIdx.x, tid = threadIdx.x;
    int beg = bbase[b], end = bbase[b + 1];
    lcnt[tid] = 0; wsum[tid] = 0.f;
    __syncthreads();
    size_t nodeBase = (size_t)(b << 8) * 32;
    for (int i = beg + tid; i < end; i += 256) {
        int2 v = ebuf[i];
        int dlow = ((unsigned)v.x) >> 24;
        unsafeAtomicAdd(&wsum[dlow], __int_as_float(v.y));   // native ds_add_f32
        int rank = atomicAdd(&lcnt[dlow], 1);                // native ds_add_u32
        int2 o; o.x = v.x & 0x00FFFFFF; o.y = v.y;
        if (rank < 32) {
            esl[nodeBase + dlow * 32 + rank] = o;
        } else {                                             // rare overflow
            int oi = atomicAdd(ovcnt, 1);
            int4 q; q.x = o.x; q.y = (b << 8) + dlow; q.z = o.y; q.w = 0;
            ovbuf[oi] = q;
        }
    }
    __syncthreads();                               // lcnt = deg, wsum = sum(w)
    float dv = rsqrtf(1.0f + wsum[tid]);           // self-loop weight 1; deg >= 1
    sdinv[tid] = dv;
    int node = (b << 8) + tid;
    if (node < N) dinv[node] = dv;
    int nNodes = N - (b << 8); if (nNodes > 256) nNodes = 256;
    // pad unused slots with {src=0, w=0}
    for (int i = tid; i < nNodes * 32; i += 256) {
        int r = i >> 5, j = i & 31;
        if (j >= lcnt[r]) { int2 z; z.x = 0; z.y = 0; esl[nodeBase + i] = z; }
    }
    // fused prep: Y rows for this bucket (8 float4 per node, contiguous)
    int limit = nNodes * 8;
    size_t base4 = ((size_t)b << 8) * 8;
    for (int i = tid; i < limit; i += 256) {
        float4 v = X4[base4 + i];
        float d = sdinv[i >> 3];
        float4 o; o.x = v.x * d; o.y = v.y * d; o.z = v.z * d; o.w = v.w * d;
        Y4[base4 + i] = o;
    }
}

// ---------------- per-layer compute ----------------

// AX[d,:] = dinv[d] * (Y[d,:] + sum_slots w * Y[src,:])
// one wave per node; 8 lanes x float4 cover the 128B row; 32 slots in 4 groups.
// All esl/self/dinv loads address-computable from wid -> chain depth 2.
__global__ __launch_bounds__(256) void k_gather(const float4* __restrict__ Y4,
                                                const int2* __restrict__ esl,
                                                const float* __restrict__ dinv,
                                                float4* __restrict__ AX4, int N) {
    int wid = (blockIdx.x * blockDim.x + threadIdx.x) >> 6;
    if (wid >= N) return;
    int lane = threadIdx.x & 63;
    int q = lane >> 3, c4 = lane & 7;
    const int2* ep = esl + (size_t)wid * 32 + q;
    int2 p0 = ep[0], p1 = ep[8], p2 = ep[16], p3 = ep[24];   // all in flight
    float di = dinv[wid];
    float4 self = Y4[(size_t)wid * 8 + c4];
    float4 y0 = Y4[(size_t)p0.x * 8 + c4];
    float4 y1 = Y4[(size_t)p1.x * 8 + c4];
    float4 y2 = Y4[(size_t)p2.x * 8 + c4];
    float4 y3 = Y4[(size_t)p3.x * 8 + c4];
    float w0 = __int_as_float(p0.y), w1 = __int_as_float(p1.y);
    float w2 = __int_as_float(p2.y), w3 = __int_as_float(p3.y);
    float4 acc1, acc2;
    if (q == 0) acc1 = self; else { acc1.x = acc1.y = acc1.z = acc1.w = 0.f; }
    acc2.x = acc2.y = acc2.z = acc2.w = 0.f;
    acc1.x += w0 * y0.x; acc1.y += w0 * y0.y; acc1.z += w0 * y0.z; acc1.w += w0 * y0.w;
    acc2.x += w1 * y1.x; acc2.y += w1 * y1.y; acc2.z += w1 * y1.z; acc2.w += w1 * y1.w;
    acc1.x += w2 * y2.x; acc1.y += w2 * y2.y; acc1.z += w2 * y2.z; acc1.w += w2 * y2.w;
    acc2.x += w3 * y3.x; acc2.y += w3 * y3.y; acc2.z += w3 * y3.z; acc2.w += w3 * y3.w;
    acc1.x += acc2.x; acc1.y += acc2.y; acc1.z += acc2.z; acc1.w += acc2.w;
#pragma unroll
    for (int off = 8; off <= 32; off <<= 1) {
        acc1.x += __shfl_xor(acc1.x, off);
        acc1.y += __shfl_xor(acc1.y, off);
        acc1.z += __shfl_xor(acc1.z, off);
        acc1.w += __shfl_xor(acc1.w, off);
    }
    if (lane < 8) {
        float4 o; o.x = acc1.x * di; o.y = acc1.y * di; o.z = acc1.z * di; o.w = acc1.w * di;
        AX4[(size_t)wid * 8 + c4] = o;
    }
}

// overflow edges (deg>32): add dinv[dst]*w*Y[src,c] into AX after gather.
// Expected count ~dozens; atomics are fine.
__global__ __launch_bounds__(256) void k_tail(const float* __restrict__ Y,
                                              const int4* __restrict__ ovbuf,
                                              const int* __restrict__ ovcnt,
                                              const float* __restrict__ dinv,
                                              float* __restrict__ AX) {
    int cnt = *ovcnt;
    int total = cnt * 32;
    int stride = gridDim.x * 256;
    for (int i = blockIdx.x * 256 + threadIdx.x; i < total; i += stride) {
        int e = i >> 5, c = i & 31;
        int4 q = ovbuf[e];
        int src = q.x, dst = q.y;
        float w = __int_as_float(q.z);
        atomicAdd(&AX[(size_t)dst * 32 + c], dinv[dst] * w * Y[(size_t)src * 32 + c]);
    }
}

// 4-node W-reuse gates: block = 128 nodes; thread (r0=tid>>3, g8=tid&7) does
// nodes r0+32j, channels g8*4..+3 for I/T/O. Each W float4 read is reused
// across 4 nodes. Epilogue in-register (bS/wcs/sdv in LDS, fast transcendentals).
__global__ __launch_bounds__(256) void k_gates(const float* __restrict__ AX,
                                               const float* __restrict__ cw,
                                               const float* __restrict__ cb,
                                               const float* __restrict__ wc,
                                               const float* __restrict__ bg,
                                               const float* __restrict__ dinv,
                                               float* __restrict__ outRaw,
                                               float* __restrict__ outY,
                                               int N, int l, int isLast) {
    __shared__ float Ws[32][96];                   // [k][gate*32 + c]
    __shared__ float Xs[128][33];
    __shared__ float bS[96];
    __shared__ float wcs[32];
    __shared__ float sdv[128];
    int tid = threadIdx.x;
    for (int i = tid; i < 3072; i += 256) {
        int k = i / 96, ccol = i - k * 96;
        int g = ccol >> 5, o = ccol & 31;
        int j = (g == 0) ? 0 : ((g == 1) ? 4 : 6); // I, T, O convs on x
        Ws[k][ccol] = cw[(((l * 8 + j) * 32) + k) * 32 + o];
    }
    if (tid < 32) {
        int c = tid;
        bS[c]      = cb[((l * 8 + 0) * 32) + c] + cb[((l * 8 + 1) * 32) + c] + bg[((l * 4 + 0) * 32) + c];
        bS[32 + c] = cb[((l * 8 + 4) * 32) + c] + cb[((l * 8 + 5) * 32) + c] + bg[((l * 4 + 2) * 32) + c];
        bS[64 + c] = cb[((l * 8 + 6) * 32) + c] + cb[((l * 8 + 7) * 32) + c] + bg[((l * 4 + 3) * 32) + c];
        wcs[c]     = wc[((l * 3 + 2) * 32) + c];
    }
    int row0 = blockIdx.x * 128;
    for (int i = tid; i < 4096; i += 256) {
        int r = i >> 5, k = i & 31; int gr = row0 + r;
        Xs[r][k] = (gr < N) ? AX[(size_t)gr * 32 + k] : 0.f;
    }
    if (tid < 128) {
        int gr = row0 + tid;
        sdv[tid] = (gr < N) ? dinv[gr] : 0.f;
    }
    __syncthreads();
    int r0 = tid >> 3, g8 = tid & 7, cbase = g8 * 4;
    float aI[4][4], aT[4][4], aO[4][4];            // [node j][channel cc]
#pragma unroll
    for (int j = 0; j < 4; j++)
#pragma unroll
        for (int cc = 0; cc < 4; cc++) { aI[j][cc] = 0.f; aT[j][cc] = 0.f; aO[j][cc] = 0.f; }
#pragma unroll 4
    for (int k = 0; k < 32; k++) {
        float4 wI = *(const float4*)&Ws[k][cbase];
        float4 wT = *(const float4*)&Ws[k][32 + cbase];
        float4 wO = *(const float4*)&Ws[k][64 + cbase];
#pragma unroll
        for (int j = 0; j < 4; j++) {
            float xv = Xs[r0 + 32 * j][k];
            aI[j][0] += xv * wI.x; aI[j][1] += xv * wI.y; aI[j][2] += xv * wI.z; aI[j][3] += xv * wI.w;
            aT[j][0] += xv * wT.x; aT[j][1] += xv * wT.y; aT[j][2] += xv * wT.z; aT[j][3] += xv * wT.w;
            aO[j][0] += xv * wO.x; aO[j][1] += xv * wO.y; aO[j][2] += xv * wO.z; aO[j][3] += xv * wO.w;
        }
    }
#pragma unroll
    for (int j = 0; j < 4; j++) {
        int r = r0 + 32 * j;
        int gn = row0 + r;
        if (gn >= N) continue;
        float di = sdv[r];
        float4 v;
        float res[4];
#pragma unroll
        for (int cc = 0; cc < 4; cc++) {
            int c = cbase + cc;
            float I = fsig(aI[j][cc] + bS[c]);
            float T = ftanh(aT[j][cc] + bS[32 + c]);
            float C = I * T;                       // C_old = 0, F-gate dead
            float O = fsig(aO[j][cc] + wcs[c] * C + bS[64 + c]);
            float val = O * ftanh(C);
            res[cc] = isLast ? val : di * val;
        }
        v.x = res[0]; v.y = res[1]; v.z = res[2]; v.w = res[3];
        float* dst = isLast ? outRaw : outY;
        *(float4*)&dst[(size_t)gn * 32 + cbase] = v;
    }
}

extern "C" void kernel_launch(void* const* d_in, const int* in_sizes, int n_in,
                              void* d_out, int out_size, void* d_ws, size_t ws_size,
                              hipStream_t stream) {
    const float* X  = (const float*)d_in[0];
    const int*   ei = (const int*)d_in[1];
    const float* ew = (const float*)d_in[2];
    const float* cw = (const float*)d_in[3];
    const float* cb = (const float*)d_in[4];
    const float* wc = (const float*)d_in[5];
    const float* bg = (const float*)d_in[6];
    int N = in_sizes[0] / 32;
    int E = in_sizes[2];
    int L = in_sizes[3] / (8 * 32 * 32);
    float* out = (float*)d_out;
    int NB = (N + 255) >> 8;

    char* p = (char*)d_ws;
    auto alloc = [&](size_t bytes) -> char* {
        char* r = p; p += (bytes + 255) & ~(size_t)255; return r;
    };
    int*   bhist     = (int*)alloc((size_t)(NB + 1) * 4);   // [NB] = ovcnt
    int*   bbase     = (int*)alloc((size_t)(NB + 1) * 4);
    int*   bfill     = (int*)alloc((size_t)NB * 4);
    float* dinv      = (float*)alloc((size_t)N * 4);
    int2*  ebuf      = (int2*)alloc((size_t)E * 8);
    int2*  esl       = (int2*)alloc((size_t)N * 32 * 8);
    int4*  ovbuf     = (int4*)alloc((size_t)65536 * 16);
    float* Y         = (float*)alloc((size_t)N * 32 * 4);
    float* AX        = (float*)alloc((size_t)N * 32 * 4);
    int*   ovcnt     = bhist + NB;

    k_zero<<<(NB + 256) / 256, 256, 0, stream>>>(bhist, NB + 1);
    k_bhist<<<512, 256, 0, stream>>>(ei, bhist, E, NB);
    k_bscan<<<1, 256, 0, stream>>>(bhist, bbase, bfill, NB, E);
    int nBin = (E + 4095) / 4096;
    k_bin<<<nBin, 256, 0, stream>>>(ei, ew, bfill, ebuf, E, NB);
    k_bucket<<<NB, 256, 0, stream>>>(ebuf, bbase, esl, ovbuf, ovcnt, dinv,
                                     (const float4*)X, (float4*)Y, N, E);

    for (int l = 0; l < L; l++) {
        k_gather<<<(N + 3) / 4, 256, 0, stream>>>((const float4*)Y, esl, dinv,
                                                  (float4*)AX, N);
        k_tail<<<16, 256, 0, stream>>>(Y, ovbuf, ovcnt, dinv, AX);
        k_gates<<<(N + 127) / 128, 256, 0, stream>>>(AX, cw, cb, wc, bg, dinv,
                                                     out, Y, N, l, l == L - 1);
    }
}